// Round 1
// baseline (812.431 us; speedup 1.0000x reference)
//
#include <hip/hip_runtime.h>
#include <hip/hip_fp16.h>

// CSWin window attention: B=32, C=128, H=W=56, windows 56x7 (392 tokens),
// 4 heads x head_dim 32. One block per (window, head) = 1024 blocks.
// Round 1: correctness-first VALU flash attention.
//   - V staged fp32 token-major flat in LDS: serves PV (index k*32+d) AND
//     the scrambled LePE conv (flat index d*392+s' -- exact identity with
//     the reference's transpose-free reshape).
//   - K staged in fp16 chunks of 56 keys (LDS budget), unpacked to fp32.
//   - Online softmax per lane (1 query per lane).

#define NTOK 392
#define HDIM 32
#define HW   3136
#define CH   128
#define KCH  56
#define NTHR 448

__global__ __launch_bounds__(NTHR) void cswin_attn_kernel(
    const float* __restrict__ x, const float* __restrict__ cw,
    const float* __restrict__ cb, float* __restrict__ out) {
  const int tid = threadIdx.x;
  const int w   = blockIdx.x >> 2;   // window 0..255
  const int hd  = blockIdx.x & 3;    // head
  const int b   = w >> 3;            // batch
  const int wc  = w & 7;             // W-window
  const int col0 = wc * 7;

  __shared__ __align__(16) float  Vs[NTOK * HDIM];   // 50176 B, token-major flat
  __shared__ __align__(16) __half Ksc[KCH * HDIM];   //  3584 B, fp16 chunk

  const size_t xQ = ((size_t)(b * 3 + 0) * CH + hd * HDIM) * HW;
  const size_t xK = ((size_t)(b * 3 + 1) * CH + hd * HDIM) * HW;
  const size_t xV = ((size_t)(b * 3 + 2) * CH + hd * HDIM) * HW;

  // ---- Stage V (fp32, flat [t*32+d]) ----
  for (int i = tid; i < NTOK * HDIM; i += NTHR) {
    int t = i >> 5, d = i & 31;
    int h = t / 7, wp = t - h * 7;
    Vs[i] = x[xV + (size_t)d * HW + h * 56 + col0 + wp];
  }

  // ---- Per-lane query state ----
  const int t = tid;
  const bool active = (t < NTOK);
  int h = 0, wp = 0, sp = 0;
  float qv[32];
  float m = -1e30f, l = 0.f, acc[32];
#pragma unroll
  for (int d = 0; d < 32; ++d) acc[d] = 0.f;

  if (active) {
    h = t / 7; wp = t - h * 7; sp = h * 56 + col0 + wp;
    const float SC = 0.17677669529663687f;  // 32^-0.5
#pragma unroll
    for (int d = 0; d < 32; ++d)
      qv[d] = x[xQ + (size_t)d * HW + sp] * SC;
  }

  // ---- Key chunks: stage fp16, online softmax + PV ----
  for (int c0 = 0; c0 < NTOK; c0 += KCH) {
    __syncthreads();  // also covers initial V staging on first iteration
    for (int i = tid; i < KCH * HDIM; i += NTHR) {
      int kk = i >> 5, d = i & 31;
      int tk = c0 + kk;
      int hk = tk / 7, wk = tk - hk * 7;
      Ksc[i] = __float2half(x[xK + (size_t)d * HW + hk * 56 + col0 + wk]);
    }
    __syncthreads();

    if (active) {
      for (int k = 0; k < KCH; ++k) {
        const uint4* kr = reinterpret_cast<const uint4*>(Ksc + k * HDIM);
        uint4 u0 = kr[0], u1 = kr[1], u2 = kr[2], u3 = kr[3];
        unsigned ku[16] = {u0.x, u0.y, u0.z, u0.w, u1.x, u1.y, u1.z, u1.w,
                           u2.x, u2.y, u2.z, u2.w, u3.x, u3.y, u3.z, u3.w};
        float s = 0.f;
#pragma unroll
        for (int j = 0; j < 16; ++j) {
          float2 kf = __half22float2(*reinterpret_cast<__half2*>(&ku[j]));
          s += qv[2 * j] * kf.x + qv[2 * j + 1] * kf.y;
        }

        float mn = fmaxf(m, s);
        float p = __expf(s - mn);
        if (mn > m) {
          float scl = __expf(m - mn);
          l *= scl;
#pragma unroll
          for (int d = 0; d < 32; ++d) acc[d] *= scl;
          m = mn;
        }
        l += p;

        const float4* vr = reinterpret_cast<const float4*>(Vs + (c0 + k) * HDIM);
#pragma unroll
        for (int j = 0; j < 8; ++j) {
          float4 v4 = vr[j];
          acc[j * 4 + 0] += p * v4.x;
          acc[j * 4 + 1] += p * v4.y;
          acc[j * 4 + 2] += p * v4.z;
          acc[j * 4 + 3] += p * v4.w;
        }
      }
    }
  }

  // ---- Epilogue: LePE (scrambled depthwise conv == flat-index reads) + store ----
  if (active) {
    float inv_l = 1.f / l;
    size_t ob = ((size_t)b * HW + sp) * CH + hd * HDIM;
#pragma unroll
    for (int dg = 0; dg < 8; ++dg) {
      float rr[4];
#pragma unroll
      for (int j = 0; j < 4; ++j) {
        int d = dg * 4 + j;
        int c = hd * HDIM + d;
        float a = cb[c];
#pragma unroll
        for (int dh = -1; dh <= 1; ++dh) {
          int hh2 = h + dh;
          if ((unsigned)hh2 < 56u) {
#pragma unroll
            for (int dw = -1; dw <= 1; ++dw) {
              int ww = wp + dw;
              if ((unsigned)ww < 7u) {
                a += cw[c * 9 + (dh + 1) * 3 + (dw + 1)] *
                     Vs[d * NTOK + hh2 * 7 + ww];
              }
            }
          }
        }
        rr[j] = acc[d] * inv_l + a;
      }
      float4 r4 = make_float4(rr[0], rr[1], rr[2], rr[3]);
      *reinterpret_cast<float4*>(out + ob + dg * 4) = r4;
    }
  }
}

extern "C" void kernel_launch(void* const* d_in, const int* in_sizes, int n_in,
                              void* d_out, int out_size, void* d_ws, size_t ws_size,
                              hipStream_t stream) {
  const float* x  = (const float*)d_in[0];
  const float* cw = (const float*)d_in[1];
  const float* cb = (const float*)d_in[2];
  float* out = (float*)d_out;
  dim3 grid(1024), block(NTHR);
  hipLaunchKernelGGL(cswin_attn_kernel, grid, block, 0, stream, x, cw, cb, out);
}

// Round 3
// 325.511 us; speedup vs baseline: 2.4959x; 2.4959x over previous
//
#include <hip/hip_runtime.h>

typedef _Float16 f16;
typedef _Float16 f16x8 __attribute__((ext_vector_type(8)));
typedef _Float16 f16x4 __attribute__((ext_vector_type(4)));
typedef float f32x4 __attribute__((ext_vector_type(4)));

#define HW    3136
#define NTOK  392
#define KSTR  40     // K row stride in f16 (80 B: 16B-aligned, 2-way bank alias = free)
#define VSTR  408    // Vt row stride in f16 (816 B: 16B-aligned, 2-way bank alias)
#define NSTEP 13
#define QSCALE 0.17677669529663687f

// CSWin window attention, MFMA version.
// Block = (window, head): S=392 tokens, D=32. 8 waves, each owns q-tiles
// wv, wv+8, wv+16, wv+24 (16 queries each; 25 tiles cover 400 rows).
// Swapped QK^T (mfma 16x16x32): lane holds P[q=lane&15][key=4*(lane>>4)+r],
// which IS the A-fragment of mfma 16x16x16 for PV -> no P transpose at all.
__global__ __launch_bounds__(512, 4) void cswin_attn_mfma(
    const float* __restrict__ x, const float* __restrict__ cw,
    const float* __restrict__ cb, float* __restrict__ out) {
  __shared__ __align__(16) f16 Kl[400 * KSTR];  // [token][d]   32000 B
  __shared__ __align__(16) f16 Vt[32 * VSTR];   // [d][token]   26112 B

  const int tid  = threadIdx.x;
  const int w    = blockIdx.x >> 2;
  const int hd   = blockIdx.x & 3;
  const int b    = w >> 3;
  const int col0 = (w & 7) * 7;

  const size_t xQ = ((size_t)(b * 3 + 0) * 128 + hd * 32) * HW;
  const size_t xK = ((size_t)(b * 3 + 1) * 128 + hd * 32) * HW;
  const size_t xV = ((size_t)(b * 3 + 2) * 128 + hd * 32) * HW;

  // ---- stage K [t][d] (zero-pad rows 392..399) ----
  for (int i = tid; i < 400 * 32; i += 512) {
    int d = i / 400, t = i - d * 400;
    float v = 0.f;
    if (t < NTOK) { int sp = (t / 7) * 56 + col0 + (t % 7); v = x[xK + (size_t)d * HW + sp]; }
    Kl[t * KSTR + d] = (f16)v;
  }
  // ---- stage Vt [d][t] (zero-pad cols 392..399) ----
  for (int i = tid; i < 400 * 32; i += 512) {
    int d = i / 400, t = i - d * 400;
    float v = 0.f;
    if (t < NTOK) { int sp = (t / 7) * 56 + col0 + (t % 7); v = x[xV + (size_t)d * HW + sp]; }
    Vt[d * VSTR + t] = (f16)v;
  }

  const int lane = tid & 63;
  const int wv   = tid >> 6;     // wave 0..7
  const int lq   = lane & 15;    // query col (QK) / d col (PV)
  const int g    = lane >> 4;    // 4-group

  // ---- Q fragments for up to 4 tiles: Q[tile*16+lq][8g..8g+7] * scale ----
  f16x8 qf[4];
#pragma unroll
  for (int qi = 0; qi < 4; ++qi) {
    int tile = wv + 8 * qi;
    if (tile < 25) {
      int qr = tile * 16 + lq; if (qr > 391) qr = 391;
      int sp = (qr / 7) * 56 + col0 + (qr % 7);
#pragma unroll
      for (int j = 0; j < 8; ++j)
        qf[qi][j] = (f16)(x[xQ + (size_t)(g * 8 + j) * HW + sp] * QSCALE);
    }
  }

  __syncthreads();

  const f32x4 zero4 = {0.f, 0.f, 0.f, 0.f};
  f32x4 acc0[4], acc1[4];
  float m_[4], ls_[4];
#pragma unroll
  for (int qi = 0; qi < 4; ++qi) { acc0[qi] = zero4; acc1[qi] = zero4; m_[qi] = -1e30f; ls_[qi] = 0.f; }

  for (int ks = 0; ks < NSTEP; ++ks) {
    const int kbase = ks * 32;
    const bool tail = (ks == NSTEP - 1);   // keys 384..399 only (chunk 0)
    // A-fragments of K (16x16x32): row kbase+lq, dims 8g..8g+7
    f16x8 kf0 = *(const f16x8*)&Kl[(kbase + lq) * KSTR + 8 * g];
    f16x8 kf1 = tail ? kf0 : *(const f16x8*)&Kl[(kbase + 16 + lq) * KSTR + 8 * g];
    // B-fragments of V (16x16x16): B[k=4g+j][n=lq] = Vt[half*16+lq][kbase+16c+4g+j]
    f16x4 vf00 = *(const f16x4*)&Vt[lq * VSTR + kbase + 4 * g];
    f16x4 vf01 = *(const f16x4*)&Vt[(16 + lq) * VSTR + kbase + 4 * g];
    f16x4 vf10 = vf00, vf11 = vf01;
    if (!tail) {
      vf10 = *(const f16x4*)&Vt[lq * VSTR + kbase + 16 + 4 * g];
      vf11 = *(const f16x4*)&Vt[(16 + lq) * VSTR + kbase + 16 + 4 * g];
    }

#pragma unroll
    for (int qi = 0; qi < 4; ++qi) {
      int tile = wv + 8 * qi;
      if (tile >= 25) continue;   // wave-uniform
      f32x4 st0 = __builtin_amdgcn_mfma_f32_16x16x32_f16(kf0, qf[qi], zero4, 0, 0, 0);
      f32x4 st1 = zero4;
      if (!tail) st1 = __builtin_amdgcn_mfma_f32_16x16x32_f16(kf1, qf[qi], zero4, 0, 0, 0);
      if (tail) {
#pragma unroll
        for (int r = 0; r < 4; ++r) st0[r] = (4 * g + r < 8) ? st0[r] : -1e30f;
      }
      float tl = fmaxf(fmaxf(st0[0], st0[1]), fmaxf(st0[2], st0[3]));
      if (!tail) tl = fmaxf(tl, fmaxf(fmaxf(st1[0], st1[1]), fmaxf(st1[2], st1[3])));
      float m = m_[qi];
      if (__any(tl > m + 6.f)) {         // rare: cross-replica max + rescale
        float tf = fmaxf(tl, __shfl_xor(tl, 16));
        tf = fmaxf(tf, __shfl_xor(tf, 32));
        float mn = fmaxf(m, tf);
        float scl = __expf(m - mn);
        ls_[qi] *= scl;
#pragma unroll
        for (int r = 0; r < 4; ++r) { acc0[qi][r] *= scl; acc1[qi][r] *= scl; }
        m = mn; m_[qi] = mn;
      }
      float p0[4], p1[4];
#pragma unroll
      for (int r = 0; r < 4; ++r) p0[r] = __expf(st0[r] - m);
      float ps = (p0[0] + p0[1]) + (p0[2] + p0[3]);
      f16x4 pa0, pa1;
#pragma unroll
      for (int r = 0; r < 4; ++r) pa0[r] = (f16)p0[r];
      acc0[qi] = __builtin_amdgcn_mfma_f32_16x16x16f16(pa0, vf00, acc0[qi], 0, 0, 0);
      acc1[qi] = __builtin_amdgcn_mfma_f32_16x16x16f16(pa0, vf01, acc1[qi], 0, 0, 0);
      if (!tail) {
#pragma unroll
        for (int r = 0; r < 4; ++r) p1[r] = __expf(st1[r] - m);
        ps += (p1[0] + p1[1]) + (p1[2] + p1[3]);
#pragma unroll
        for (int r = 0; r < 4; ++r) pa1[r] = (f16)p1[r];
        acc0[qi] = __builtin_amdgcn_mfma_f32_16x16x16f16(pa1, vf10, acc0[qi], 0, 0, 0);
        acc1[qi] = __builtin_amdgcn_mfma_f32_16x16x16f16(pa1, vf11, acc1[qi], 0, 0, 0);
      }
      ls_[qi] += ps;   // per-replica partial sum; cross-replica reduce at epilogue
    }
  }

  // ---- per-lane conv weights for channels lq and 16+lq (epilogue-only regs) ----
  float cw0[9], cw1[9];
  {
    int c0 = hd * 32 + lq;
#pragma unroll
    for (int k = 0; k < 9; ++k) { cw0[k] = cw[c0 * 9 + k]; cw1[k] = cw[(c0 + 16) * 9 + k]; }
  }
  float cb0 = cb[hd * 32 + lq], cb1 = cb[hd * 32 + 16 + lq];

  // ---- epilogue: normalize + LePE + store ----
#pragma unroll
  for (int qi = 0; qi < 4; ++qi) {
    int tile = wv + 8 * qi;
    if (tile >= 25) continue;
    float ls = ls_[qi];
    ls += __shfl_xor(ls, 16);
    ls += __shfl_xor(ls, 32);
    float inv = 1.f / ls;              // every lane: full sum for ITS query lq
    float invq[4];
#pragma unroll
    for (int r = 0; r < 4; ++r) invq[r] = __shfl(inv, 4 * g + r);  // inv for query 4g+r

    int qb = tile * 16;
#pragma unroll
    for (int r = 0; r < 4; ++r) {
      int q = qb + 4 * g + r;
      if (q >= NTOK) continue;
      int hq = q / 7, wq = q - hq * 7;
      size_t ob = ((size_t)b * HW + hq * 56 + col0 + wq) * 128 + hd * 32;
#pragma unroll
      for (int h = 0; h < 2; ++h) {
        int d = h * 16 + lq;
        float a = h ? cb1 : cb0;
        int fbase = d * NTOK + q;      // LePE identity: channel grid pos s' == token idx
#pragma unroll
        for (int dh = -1; dh <= 1; ++dh) {
          bool hv = (unsigned)(hq + dh) < 56u;
#pragma unroll
          for (int dw = -1; dw <= 1; ++dw) {
            bool vv = hv && ((unsigned)(wq + dw) < 7u);
            int f = vv ? (fbase + dh * 7 + dw) : fbase;
            float vtap = (float)Vt[(f & 31) * VSTR + (f >> 5)];
            float wt = vv ? (h ? cw1[(dh + 1) * 3 + dw + 1] : cw0[(dh + 1) * 3 + dw + 1]) : 0.f;
            a = fmaf(wt, vtap, a);
          }
        }
        float res = (h ? acc1[qi][r] : acc0[qi][r]) * invq[r] + a;
        out[ob + d] = res;
      }
    }
  }
}

extern "C" void kernel_launch(void* const* d_in, const int* in_sizes, int n_in,
                              void* d_out, int out_size, void* d_ws, size_t ws_size,
                              hipStream_t stream) {
  const float* x  = (const float*)d_in[0];
  const float* cw = (const float*)d_in[1];
  const float* cb = (const float*)d_in[2];
  float* out = (float*)d_out;
  hipLaunchKernelGGL(cswin_attn_mfma, dim3(1024), dim3(512), 0, stream, x, cw, cb, out);
}